// Round 7
// baseline (839.434 us; speedup 1.0000x reference)
//
#include <hip/hip_runtime.h>
#include <math.h>
#include <stdint.h>
#include <stddef.h>

#define NB 8
#define NC 256
#define NN 4096
#define BN_EPS 1e-5f
#define LOG2E 1.44269504088896340736f
#define THR 24.0f

typedef unsigned short u16;
typedef __attribute__((ext_vector_type(4))) unsigned short u16x4;
typedef __attribute__((ext_vector_type(8))) short bf16x8;   // 8 bf16 = 4 VGPR
typedef __attribute__((ext_vector_type(4))) float f32x4;

static __device__ __forceinline__ float4 ld4(const float* p) { return *(const float4*)p; }
static __device__ __forceinline__ void st4(float* p, float4 v) { *(float4*)p = v; }
static __device__ __forceinline__ u16 f2bf(float f) {
  uint32_t u = __float_as_uint(f);
  return (u16)((u + 0x7FFFu + ((u >> 16) & 1u)) >> 16);   // RNE
}
static __device__ __forceinline__ u16 f2bf_trunc(float f) {
  return (u16)(__float_as_uint(f) >> 16);                 // truncate (P only)
}

// ---------------------------------------------------------------------------
// Kernel 1: fused QKV 1x1-conv + BN + ReLU. fp32 GEMM, bf16 outputs.
//   q-branch BN constants folded with log2e so attention can use exp2.
//   q_bf,k_bf : [B][N][32] bf16 ; v_bf : [B][C][N] bf16
// ---------------------------------------------------------------------------
__global__ __launch_bounds__(256) void qkv_fused(
    const float* __restrict__ x,
    const float* __restrict__ wq, const float* __restrict__ bq,
    const float* __restrict__ gq, const float* __restrict__ betaq,
    const float* __restrict__ mq, const float* __restrict__ vq,
    const float* __restrict__ wk, const float* __restrict__ bk,
    const float* __restrict__ gk, const float* __restrict__ betak,
    const float* __restrict__ mk, const float* __restrict__ vk,
    const float* __restrict__ wv, const float* __restrict__ bv,
    const float* __restrict__ gv, const float* __restrict__ betav,
    const float* __restrict__ mv, const float* __restrict__ vv,
    u16* __restrict__ q_bf, u16* __restrict__ k_bf, u16* __restrict__ v_bf)
{
  __shared__ __align__(16) float smem[8704];
  float* sX = smem;          // [32 c][128 n]
  float* sW = smem + 4096;   // [64 o][36]
  float* sT = smem;          // epilogue [128 n][68]

  const int tid   = threadIdx.x;
  const int bx    = blockIdx.x;
  const int b     = bx & 7;
  const int rem   = bx >> 3;
  const int ntile = rem & 31;
  const int otile = rem >> 5;
  const int n0    = ntile * 128;
  const int o0    = otile * 64;

  const int to = tid >> 4;
  const int tn = tid & 15;

  float acc[4][2][4];
#pragma unroll
  for (int j = 0; j < 4; ++j)
#pragma unroll
    for (int r = 0; r < 2; ++r)
#pragma unroll
      for (int e = 0; e < 4; ++e) acc[j][r][e] = 0.f;

  const float* xb = x + (size_t)b * NC * NN + n0;

  for (int ch = 0; ch < 8; ++ch) {
    const int c0 = ch * 32;
#pragma unroll
    for (int p = 0; p < 4; ++p) {
      int f = p * 256 + tid;
      int row = f >> 5, col4 = f & 31;
      st4(sX + row * 128 + col4 * 4, ld4(xb + (size_t)(c0 + row) * NN + col4 * 4));
    }
#pragma unroll
    for (int p = 0; p < 2; ++p) {
      int f = p * 256 + tid;
      int row = f >> 3, col4 = f & 7;
      int o = o0 + row;
      const float* wrow;
      if (o < 32)      wrow = wq + o * NC;
      else if (o < 64) wrow = wk + (o - 32) * NC;
      else             wrow = wv + (o - 64) * NC;
      st4(sW + row * 36 + col4 * 4, ld4(wrow + c0 + col4 * 4));
    }
    __syncthreads();

    for (int cc = 0; cc < 8; ++cc) {
      float wr[4][4];
#pragma unroll
      for (int j = 0; j < 4; ++j) {
        float4 t = ld4(sW + (to * 4 + j) * 36 + cc * 4);
        wr[j][0] = t.x; wr[j][1] = t.y; wr[j][2] = t.z; wr[j][3] = t.w;
      }
      float xr[4][2][4];
#pragma unroll
      for (int lc = 0; lc < 4; ++lc)
#pragma unroll
        for (int r = 0; r < 2; ++r) {
          float4 t = ld4(sX + (cc * 4 + lc) * 128 + tn * 4 + r * 64);
          xr[lc][r][0] = t.x; xr[lc][r][1] = t.y; xr[lc][r][2] = t.z; xr[lc][r][3] = t.w;
        }
#pragma unroll
      for (int j = 0; j < 4; ++j)
#pragma unroll
        for (int lc = 0; lc < 4; ++lc)
#pragma unroll
          for (int r = 0; r < 2; ++r)
#pragma unroll
            for (int e = 0; e < 4; ++e)
              acc[j][r][e] = fmaf(wr[j][lc], xr[lc][r][e], acc[j][r][e]);
    }
    __syncthreads();
  }

  if (otile == 0) {
#pragma unroll
    for (int j = 0; j < 4; ++j) {
      int o = to * 4 + j;
      float bias, g, beta, mean, var;
      if (o < 32) { int d = o;      bias = bq[d]; g = gq[d]; beta = betaq[d]; mean = mq[d]; var = vq[d]; }
      else        { int d = o - 32; bias = bk[d]; g = gk[d]; beta = betak[d]; mean = mk[d]; var = vk[d]; }
      float alpha = g * rsqrtf(var + BN_EPS);
      float delta = (bias - mean) * alpha + beta;
      if (o < 32) { alpha *= LOG2E; delta *= LOG2E; }   // q pre-scaled for exp2 softmax
#pragma unroll
      for (int r = 0; r < 2; ++r)
#pragma unroll
        for (int e = 0; e < 4; ++e) {
          float y = fmaxf(fmaf(acc[j][r][e], alpha, delta), 0.f);
          int n = tn * 4 + r * 64 + e;
          sT[n * 68 + to * 4 + j] = y;
        }
    }
    __syncthreads();
    const size_t nrow = (size_t)b * NN + n0;
#pragma unroll
    for (int p = 0; p < 8; ++p) {
      int f = p * 256 + tid;
      int n = f >> 4, col4 = f & 15;
      float4 t = ld4(sT + n * 68 + col4 * 4);
      u16x4 h = { f2bf(t.x), f2bf(t.y), f2bf(t.z), f2bf(t.w) };
      if (col4 < 8) *(u16x4*)(q_bf + (nrow + n) * 32 + col4 * 4) = h;
      else          *(u16x4*)(k_bf + (nrow + n) * 32 + (col4 - 8) * 4) = h;
    }
  } else {
#pragma unroll
    for (int j = 0; j < 4; ++j) {
      int c = (otile - 1) * 64 + to * 4 + j;
      float alpha = gv[c] * rsqrtf(vv[c] + BN_EPS);
      float delta = (bv[c] - mv[c]) * alpha + betav[c];
#pragma unroll
      for (int r = 0; r < 2; ++r) {
        u16x4 h;
#pragma unroll
        for (int e = 0; e < 4; ++e)
          h[e] = f2bf(fmaxf(fmaf(acc[j][r][e], alpha, delta), 0.f));
        int n = n0 + tn * 4 + r * 64;
        *(u16x4*)(v_bf + ((size_t)b * NC + c) * NN + n) = h;
      }
    }
  }
}

// ---------------------------------------------------------------------------
// Kernel 2: MFMA flash attention, R6: deferred-max softmax, zero barriers.
//   WG = 4 independent waves, each: 32 q-rows x all 64 j x its 64 channels.
//   Fast path per tile: NO cross-lane reduction -- per-lane check vs m+THR
//   (+__any ballot); P = exp2(s - m) directly; l kept as per-lane partials,
//   reduced once at the end. Rare slow path: shfl max-reduce + rescale.
//   Private swizzled sP per wave; blk0/blk1 sequential to cap VGPR (<128).
// ---------------------------------------------------------------------------
__global__ __launch_bounds__(256, 4) void attn_mfma(
    const u16* __restrict__ q_bf, const u16* __restrict__ k_bf,
    const u16* __restrict__ v_bf, const float* __restrict__ x,
    const float* __restrict__ gamma, float* __restrict__ out)
{
  __shared__ u16 sP[4 * 32 * 64];             // per-wave swizzled P tiles

  const int tid = threadIdx.x;
  const int w   = tid >> 6;
  const int l   = tid & 63;
  const int xl  = l & 15;
  const int g   = l >> 4;
  const int b   = blockIdx.x & 7;
  const int rt  = blockIdx.x >> 3;            // 0..127
  const int i0  = rt * 32;

  u16* sPw = sP + w * 2048;

  const u16* qb   = q_bf + ((size_t)b * NN + i0) * 32;
  const u16* kb_l = k_bf + (size_t)b * NN * 32 + (size_t)xl * 32 + 8 * g;
  const u16* vb_l = v_bf + ((size_t)b * NC + w * 64) * NN + (size_t)xl * NN + 8 * g;

  // Q A-frags: lane holds Q[i = blk*16+xl][k = 8g..8g+7]
  bf16x8 qf[2];
  qf[0] = *(const bf16x8*)(qb + (size_t)xl * 32 + 8 * g);
  qf[1] = *(const bf16x8*)(qb + (size_t)(16 + xl) * 32 + 8 * g);

  f32x4 acc[2][4];
#pragma unroll
  for (int blk = 0; blk < 2; ++blk)
#pragma unroll
    for (int ct = 0; ct < 4; ++ct)
      acc[blk][ct] = (f32x4){0.f, 0.f, 0.f, 0.f};

  float mrow[2][4], lsum[2][4];
#pragma unroll
  for (int blk = 0; blk < 2; ++blk)
#pragma unroll
    for (int r = 0; r < 4; ++r) { mrow[blk][r] = -INFINITY; lsum[blk][r] = 0.f; }

  for (int jt64 = 0; jt64 < 64; ++jt64) {
    const int j0 = jt64 * 64;

    // K frags for all 4 j-subtiles (this wave computes full S redundantly)
    bf16x8 kf[4];
#pragma unroll
    for (int jb = 0; jb < 4; ++jb)
      kf[jb] = *(const bf16x8*)(kb_l + (size_t)(j0 + 16 * jb) * 32);
    // V frags, jt2=0 half (issued early; latency hides under blk0 softmax)
    bf16x8 vfA[4];
#pragma unroll
    for (int ct = 0; ct < 4; ++ct)
      vfA[ct] = *(const bf16x8*)(vb_l + (size_t)(ct * 16) * NN + j0);

    // ================= blk 0 =================
    f32x4 s0[4];
#pragma unroll
    for (int jb = 0; jb < 4; ++jb)
      s0[jb] = __builtin_amdgcn_mfma_f32_16x16x32_bf16(qf[0], kf[jb], (f32x4){0.f,0.f,0.f,0.f}, 0, 0, 0);
    {
      float mx[4];
#pragma unroll
      for (int r = 0; r < 4; ++r)
        mx[r] = fmaxf(fmaxf(s0[0][r], s0[1][r]), fmaxf(s0[2][r], s0[3][r]));
      bool need = false;
#pragma unroll
      for (int r = 0; r < 4; ++r) need = need || (mx[r] > mrow[0][r] + THR);
      if (__any(need)) {                       // rare slow path
#pragma unroll
        for (int msk = 1; msk < 16; msk <<= 1)
#pragma unroll
          for (int r = 0; r < 4; ++r) mx[r] = fmaxf(mx[r], __shfl_xor(mx[r], msk));
#pragma unroll
        for (int r = 0; r < 4; ++r) {
          float mn = fmaxf(mrow[0][r], mx[r]);
          float sc = exp2f(mrow[0][r] - mn);
          mrow[0][r] = mn; lsum[0][r] *= sc;
#pragma unroll
          for (int ct = 0; ct < 4; ++ct) acc[0][ct][r] *= sc;
        }
      }
#pragma unroll
      for (int jb = 0; jb < 4; ++jb)
#pragma unroll
        for (int r = 0; r < 4; ++r) {
          float p = exp2f(s0[jb][r] - mrow[0][r]);
          lsum[0][r] += p;
          int row = 4 * g + r;
          sPw[row * 64 + ((16 * jb + xl) ^ ((row & 7) << 3))] = f2bf_trunc(p);
        }
    }
    // PV blk0 x jt2=0
    {
      int row = xl;
      bf16x8 pf = *(const bf16x8*)(sPw + row * 64 + ((8 * g) ^ ((row & 7) << 3)));
#pragma unroll
      for (int ct = 0; ct < 4; ++ct)
        acc[0][ct] = __builtin_amdgcn_mfma_f32_16x16x32_bf16(pf, vfA[ct], acc[0][ct], 0, 0, 0);
    }

    // ================= blk 1 =================
    f32x4 s1[4];
#pragma unroll
    for (int jb = 0; jb < 4; ++jb)
      s1[jb] = __builtin_amdgcn_mfma_f32_16x16x32_bf16(qf[1], kf[jb], (f32x4){0.f,0.f,0.f,0.f}, 0, 0, 0);
    // V frags, jt2=1 half (hides under blk1 softmax)
    bf16x8 vfB[4];
#pragma unroll
    for (int ct = 0; ct < 4; ++ct)
      vfB[ct] = *(const bf16x8*)(vb_l + (size_t)(ct * 16) * NN + j0 + 32);
    {
      float mx[4];
#pragma unroll
      for (int r = 0; r < 4; ++r)
        mx[r] = fmaxf(fmaxf(s1[0][r], s1[1][r]), fmaxf(s1[2][r], s1[3][r]));
      bool need = false;
#pragma unroll
      for (int r = 0; r < 4; ++r) need = need || (mx[r] > mrow[1][r] + THR);
      if (__any(need)) {
#pragma unroll
        for (int msk = 1; msk < 16; msk <<= 1)
#pragma unroll
          for (int r = 0; r < 4; ++r) mx[r] = fmaxf(mx[r], __shfl_xor(mx[r], msk));
#pragma unroll
        for (int r = 0; r < 4; ++r) {
          float mn = fmaxf(mrow[1][r], mx[r]);
          float sc = exp2f(mrow[1][r] - mn);
          mrow[1][r] = mn; lsum[1][r] *= sc;
#pragma unroll
          for (int ct = 0; ct < 4; ++ct) acc[1][ct][r] *= sc;
        }
      }
#pragma unroll
      for (int jb = 0; jb < 4; ++jb)
#pragma unroll
        for (int r = 0; r < 4; ++r) {
          float p = exp2f(s1[jb][r] - mrow[1][r]);
          lsum[1][r] += p;
          int row = 16 + 4 * g + r;
          sPw[row * 64 + ((16 * jb + xl) ^ ((row & 7) << 3))] = f2bf_trunc(p);
        }
    }
    // PV blk1 x jt2=0 ; blk0 x jt2=1 ; blk1 x jt2=1
    {
      int row = 16 + xl;
      bf16x8 pf = *(const bf16x8*)(sPw + row * 64 + ((8 * g) ^ ((row & 7) << 3)));
#pragma unroll
      for (int ct = 0; ct < 4; ++ct)
        acc[1][ct] = __builtin_amdgcn_mfma_f32_16x16x32_bf16(pf, vfA[ct], acc[1][ct], 0, 0, 0);
    }
    {
      int row = xl;
      bf16x8 pf = *(const bf16x8*)(sPw + row * 64 + ((32 + 8 * g) ^ ((row & 7) << 3)));
#pragma unroll
      for (int ct = 0; ct < 4; ++ct)
        acc[0][ct] = __builtin_amdgcn_mfma_f32_16x16x32_bf16(pf, vfB[ct], acc[0][ct], 0, 0, 0);
    }
    {
      int row = 16 + xl;
      bf16x8 pf = *(const bf16x8*)(sPw + row * 64 + ((32 + 8 * g) ^ ((row & 7) << 3)));
#pragma unroll
      for (int ct = 0; ct < 4; ++ct)
        acc[1][ct] = __builtin_amdgcn_mfma_f32_16x16x32_bf16(pf, vfB[ct], acc[1][ct], 0, 0, 0);
    }
  }

  // ---- final l reduction (once) ----
#pragma unroll
  for (int msk = 1; msk < 16; msk <<= 1)
#pragma unroll
    for (int blk = 0; blk < 2; ++blk)
#pragma unroll
      for (int r = 0; r < 4; ++r)
        lsum[blk][r] += __shfl_xor(lsum[blk][r], msk);

  float linv[2][4];
#pragma unroll
  for (int blk = 0; blk < 2; ++blk)
#pragma unroll
    for (int r = 0; r < 4; ++r) linv[blk][r] = 1.f / lsum[blk][r];

  // ---- epilogue: out = gamma * acc/l + x, direct float4 RMW ----
  const float gm = gamma[0];
#pragma unroll
  for (int blk = 0; blk < 2; ++blk)
#pragma unroll
    for (int ct = 0; ct < 4; ++ct) {
      int c = w * 64 + ct * 16 + xl;
      size_t off = ((size_t)b * NC + c) * NN + i0 + blk * 16 + 4 * g;
      float4 xv = ld4(x + off);
      float4 o4;
      o4.x = fmaf(gm, acc[blk][ct][0] * linv[blk][0], xv.x);
      o4.y = fmaf(gm, acc[blk][ct][1] * linv[blk][1], xv.y);
      o4.z = fmaf(gm, acc[blk][ct][2] * linv[blk][2], xv.z);
      o4.w = fmaf(gm, acc[blk][ct][3] * linv[blk][3], xv.w);
      st4(out + off, o4);
    }
}

// ---------------------------------------------------------------------------
extern "C" void kernel_launch(void* const* d_in, const int* in_sizes, int n_in,
                              void* d_out, int out_size, void* d_ws, size_t ws_size,
                              hipStream_t stream) {
  const float* x     = (const float*)d_in[0];
  const float* wq    = (const float*)d_in[1];
  const float* bq    = (const float*)d_in[2];
  const float* gq    = (const float*)d_in[3];
  const float* betaq = (const float*)d_in[4];
  const float* mq    = (const float*)d_in[5];
  const float* vq    = (const float*)d_in[6];
  const float* wk    = (const float*)d_in[7];
  const float* bk    = (const float*)d_in[8];
  const float* gk    = (const float*)d_in[9];
  const float* betak = (const float*)d_in[10];
  const float* mk    = (const float*)d_in[11];
  const float* vk    = (const float*)d_in[12];
  const float* wv    = (const float*)d_in[13];
  const float* bv    = (const float*)d_in[14];
  const float* gv    = (const float*)d_in[15];
  const float* betav = (const float*)d_in[16];
  const float* mv    = (const float*)d_in[17];
  const float* vv    = (const float*)d_in[18];
  const float* gamma = (const float*)d_in[19];
  float* out = (float*)d_out;

  u16* q_bf = (u16*)d_ws;
  u16* k_bf = q_bf + (size_t)NB * NN * 32;
  u16* v_bf = k_bf + (size_t)NB * NN * 32;

  qkv_fused<<<dim3(1280), dim3(256), 0, stream>>>(
      x, wq, bq, gq, betaq, mq, vq,
      wk, bk, gk, betak, mk, vk,
      wv, bv, gv, betav, mv, vv,
      q_bf, k_bf, v_bf);

  attn_mfma<<<dim3(1024), dim3(256), 0, stream>>>(q_bf, k_bf, v_bf, x, gamma, out);
}

// Round 8
// 482.137 us; speedup vs baseline: 1.7411x; 1.7411x over previous
//
#include <hip/hip_runtime.h>
#include <math.h>
#include <stdint.h>
#include <stddef.h>

#define NB 8
#define NC 256
#define NN 4096
#define BN_EPS 1e-5f
#define LOG2E 1.44269504088896340736f
#define THR 24.0f

typedef unsigned short u16;
typedef __attribute__((ext_vector_type(4))) unsigned short u16x4;
typedef __attribute__((ext_vector_type(8))) short bf16x8;   // 8 bf16 = 4 VGPR
typedef __attribute__((ext_vector_type(4))) float f32x4;

static __device__ __forceinline__ float4 ld4(const float* p) { return *(const float4*)p; }
static __device__ __forceinline__ void st4(float* p, float4 v) { *(float4*)p = v; }
static __device__ __forceinline__ u16 f2bf(float f) {
  uint32_t u = __float_as_uint(f);
  return (u16)((u + 0x7FFFu + ((u >> 16) & 1u)) >> 16);   // RNE
}
static __device__ __forceinline__ u16 f2bf_trunc(float f) {
  return (u16)(__float_as_uint(f) >> 16);                 // truncate (P only)
}

// ---------------------------------------------------------------------------
// Kernel 1: fused QKV 1x1-conv + BN + ReLU. fp32 GEMM, bf16 outputs.
//   q-branch BN constants folded with log2e so attention can use exp2.
//   q_bf,k_bf : [B][N][32] bf16 ; v_bf : [B][C][N] bf16   (unchanged)
// ---------------------------------------------------------------------------
__global__ __launch_bounds__(256) void qkv_fused(
    const float* __restrict__ x,
    const float* __restrict__ wq, const float* __restrict__ bq,
    const float* __restrict__ gq, const float* __restrict__ betaq,
    const float* __restrict__ mq, const float* __restrict__ vq,
    const float* __restrict__ wk, const float* __restrict__ bk,
    const float* __restrict__ gk, const float* __restrict__ betak,
    const float* __restrict__ mk, const float* __restrict__ vk,
    const float* __restrict__ wv, const float* __restrict__ bv,
    const float* __restrict__ gv, const float* __restrict__ betav,
    const float* __restrict__ mv, const float* __restrict__ vv,
    u16* __restrict__ q_bf, u16* __restrict__ k_bf, u16* __restrict__ v_bf)
{
  __shared__ __align__(16) float smem[8704];
  float* sX = smem;          // [32 c][128 n]
  float* sW = smem + 4096;   // [64 o][36]
  float* sT = smem;          // epilogue [128 n][68]

  const int tid   = threadIdx.x;
  const int bx    = blockIdx.x;
  const int b     = bx & 7;
  const int rem   = bx >> 3;
  const int ntile = rem & 31;
  const int otile = rem >> 5;
  const int n0    = ntile * 128;
  const int o0    = otile * 64;

  const int to = tid >> 4;
  const int tn = tid & 15;

  float acc[4][2][4];
#pragma unroll
  for (int j = 0; j < 4; ++j)
#pragma unroll
    for (int r = 0; r < 2; ++r)
#pragma unroll
      for (int e = 0; e < 4; ++e) acc[j][r][e] = 0.f;

  const float* xb = x + (size_t)b * NC * NN + n0;

  for (int ch = 0; ch < 8; ++ch) {
    const int c0 = ch * 32;
#pragma unroll
    for (int p = 0; p < 4; ++p) {
      int f = p * 256 + tid;
      int row = f >> 5, col4 = f & 31;
      st4(sX + row * 128 + col4 * 4, ld4(xb + (size_t)(c0 + row) * NN + col4 * 4));
    }
#pragma unroll
    for (int p = 0; p < 2; ++p) {
      int f = p * 256 + tid;
      int row = f >> 3, col4 = f & 7;
      int o = o0 + row;
      const float* wrow;
      if (o < 32)      wrow = wq + o * NC;
      else if (o < 64) wrow = wk + (o - 32) * NC;
      else             wrow = wv + (o - 64) * NC;
      st4(sW + row * 36 + col4 * 4, ld4(wrow + c0 + col4 * 4));
    }
    __syncthreads();

    for (int cc = 0; cc < 8; ++cc) {
      float wr[4][4];
#pragma unroll
      for (int j = 0; j < 4; ++j) {
        float4 t = ld4(sW + (to * 4 + j) * 36 + cc * 4);
        wr[j][0] = t.x; wr[j][1] = t.y; wr[j][2] = t.z; wr[j][3] = t.w;
      }
      float xr[4][2][4];
#pragma unroll
      for (int lc = 0; lc < 4; ++lc)
#pragma unroll
        for (int r = 0; r < 2; ++r) {
          float4 t = ld4(sX + (cc * 4 + lc) * 128 + tn * 4 + r * 64);
          xr[lc][r][0] = t.x; xr[lc][r][1] = t.y; xr[lc][r][2] = t.z; xr[lc][r][3] = t.w;
        }
#pragma unroll
      for (int j = 0; j < 4; ++j)
#pragma unroll
        for (int lc = 0; lc < 4; ++lc)
#pragma unroll
          for (int r = 0; r < 2; ++r)
#pragma unroll
            for (int e = 0; e < 4; ++e)
              acc[j][r][e] = fmaf(wr[j][lc], xr[lc][r][e], acc[j][r][e]);
    }
    __syncthreads();
  }

  if (otile == 0) {
#pragma unroll
    for (int j = 0; j < 4; ++j) {
      int o = to * 4 + j;
      float bias, g, beta, mean, var;
      if (o < 32) { int d = o;      bias = bq[d]; g = gq[d]; beta = betaq[d]; mean = mq[d]; var = vq[d]; }
      else        { int d = o - 32; bias = bk[d]; g = gk[d]; beta = betak[d]; mean = mk[d]; var = vk[d]; }
      float alpha = g * rsqrtf(var + BN_EPS);
      float delta = (bias - mean) * alpha + beta;
      if (o < 32) { alpha *= LOG2E; delta *= LOG2E; }   // q pre-scaled for exp2 softmax
#pragma unroll
      for (int r = 0; r < 2; ++r)
#pragma unroll
        for (int e = 0; e < 4; ++e) {
          float y = fmaxf(fmaf(acc[j][r][e], alpha, delta), 0.f);
          int n = tn * 4 + r * 64 + e;
          sT[n * 68 + to * 4 + j] = y;
        }
    }
    __syncthreads();
    const size_t nrow = (size_t)b * NN + n0;
#pragma unroll
    for (int p = 0; p < 8; ++p) {
      int f = p * 256 + tid;
      int n = f >> 4, col4 = f & 15;
      float4 t = ld4(sT + n * 68 + col4 * 4);
      u16x4 h = { f2bf(t.x), f2bf(t.y), f2bf(t.z), f2bf(t.w) };
      if (col4 < 8) *(u16x4*)(q_bf + (nrow + n) * 32 + col4 * 4) = h;
      else          *(u16x4*)(k_bf + (nrow + n) * 32 + (col4 - 8) * 4) = h;
    }
  } else {
#pragma unroll
    for (int j = 0; j < 4; ++j) {
      int c = (otile - 1) * 64 + to * 4 + j;
      float alpha = gv[c] * rsqrtf(vv[c] + BN_EPS);
      float delta = (bv[c] - mv[c]) * alpha + betav[c];
#pragma unroll
      for (int r = 0; r < 2; ++r) {
        u16x4 h;
#pragma unroll
        for (int e = 0; e < 4; ++e)
          h[e] = f2bf(fmaxf(fmaf(acc[j][r][e], alpha, delta), 0.f));
        int n = n0 + tn * 4 + r * 64;
        *(u16x4*)(v_bf + ((size_t)b * NC + c) * NN + n) = h;
      }
    }
  }
}

// ---------------------------------------------------------------------------
// Kernel 2: MFMA flash attention, R8: deferred-max softmax + JT=32 tiles to
//   keep VGPR < 128 (R7's JT=64 version spilled: WRITE_SIZE 1.1 GB scratch).
//   WG = 4 independent waves, zero barriers. Per iter: kf[2], vf[4], s[2]
//   per blk; blk S/P phases complete before PV so s/kf die early.
//   sP [32][64] per wave, iteration parity picks the 32-col half (same
//   swizzle/addressing as the proven conflict-free R6 layout).
// ---------------------------------------------------------------------------
__global__ __launch_bounds__(256, 4) void attn_mfma(
    const u16* __restrict__ q_bf, const u16* __restrict__ k_bf,
    const u16* __restrict__ v_bf, const float* __restrict__ x,
    const float* __restrict__ gamma, float* __restrict__ out)
{
  __shared__ u16 sP[4 * 32 * 64];             // per-wave swizzled P tiles

  const int tid = threadIdx.x;
  const int w   = tid >> 6;
  const int l   = tid & 63;
  const int xl  = l & 15;
  const int g   = l >> 4;
  const int b   = blockIdx.x & 7;
  const int rt  = blockIdx.x >> 3;            // 0..127
  const int i0  = rt * 32;

  u16* sPw = sP + w * 2048;

  const u16* qb   = q_bf + ((size_t)b * NN + i0) * 32;
  const u16* kb_l = k_bf + (size_t)b * NN * 32 + (size_t)xl * 32 + 8 * g;
  const u16* vb_l = v_bf + ((size_t)b * NC + w * 64) * NN + (size_t)xl * NN + 8 * g;

  // Q A-frags: lane holds Q[i = blk*16+xl][k = 8g..8g+7]
  bf16x8 qf[2];
  qf[0] = *(const bf16x8*)(qb + (size_t)xl * 32 + 8 * g);
  qf[1] = *(const bf16x8*)(qb + (size_t)(16 + xl) * 32 + 8 * g);

  f32x4 acc[2][4];
#pragma unroll
  for (int blk = 0; blk < 2; ++blk)
#pragma unroll
    for (int ct = 0; ct < 4; ++ct)
      acc[blk][ct] = (f32x4){0.f, 0.f, 0.f, 0.f};

  float mrow[2][4], lsum[2][4];
#pragma unroll
  for (int blk = 0; blk < 2; ++blk)
#pragma unroll
    for (int r = 0; r < 4; ++r) { mrow[blk][r] = -INFINITY; lsum[blk][r] = 0.f; }

  for (int jt32 = 0; jt32 < 128; ++jt32) {
    const int j0  = jt32 * 32;
    const int hof = (jt32 & 1) * 32;          // which 32-col half of sP

    // K frags (2 j-subtiles) + V frags (issued early, hide under softmax)
    bf16x8 kf0 = *(const bf16x8*)(kb_l + (size_t)j0 * 32);
    bf16x8 kf1 = *(const bf16x8*)(kb_l + (size_t)(j0 + 16) * 32);
    bf16x8 vf[4];
#pragma unroll
    for (int ct = 0; ct < 4; ++ct)
      vf[ct] = *(const bf16x8*)(vb_l + (size_t)(ct * 16) * NN + j0);

    // ---- blk0: S, deferred-max, P ----
    {
      f32x4 sa = __builtin_amdgcn_mfma_f32_16x16x32_bf16(qf[0], kf0, (f32x4){0.f,0.f,0.f,0.f}, 0, 0, 0);
      f32x4 sb = __builtin_amdgcn_mfma_f32_16x16x32_bf16(qf[0], kf1, (f32x4){0.f,0.f,0.f,0.f}, 0, 0, 0);
      float mx[4];
#pragma unroll
      for (int r = 0; r < 4; ++r) mx[r] = fmaxf(sa[r], sb[r]);
      bool need = false;
#pragma unroll
      for (int r = 0; r < 4; ++r) need = need || (mx[r] > mrow[0][r] + THR);
      if (__any(need)) {                       // rare slow path
#pragma unroll
        for (int msk = 1; msk < 16; msk <<= 1)
#pragma unroll
          for (int r = 0; r < 4; ++r) mx[r] = fmaxf(mx[r], __shfl_xor(mx[r], msk));
#pragma unroll
        for (int r = 0; r < 4; ++r) {
          float mn = fmaxf(mrow[0][r], mx[r]);
          float sc = exp2f(mrow[0][r] - mn);
          mrow[0][r] = mn; lsum[0][r] *= sc;
#pragma unroll
          for (int ct = 0; ct < 4; ++ct) acc[0][ct][r] *= sc;
        }
      }
#pragma unroll
      for (int r = 0; r < 4; ++r) {
        int row = 4 * g + r;
        int sw  = (row & 7) << 3;
        float pa = exp2f(sa[r] - mrow[0][r]);
        float pb = exp2f(sb[r] - mrow[0][r]);
        lsum[0][r] += pa + pb;
        sPw[row * 64 + ((hof + xl) ^ sw)]      = f2bf_trunc(pa);
        sPw[row * 64 + ((hof + 16 + xl) ^ sw)] = f2bf_trunc(pb);
      }
    }

    // ---- blk1: S, deferred-max, P ----
    {
      f32x4 sa = __builtin_amdgcn_mfma_f32_16x16x32_bf16(qf[1], kf0, (f32x4){0.f,0.f,0.f,0.f}, 0, 0, 0);
      f32x4 sb = __builtin_amdgcn_mfma_f32_16x16x32_bf16(qf[1], kf1, (f32x4){0.f,0.f,0.f,0.f}, 0, 0, 0);
      float mx[4];
#pragma unroll
      for (int r = 0; r < 4; ++r) mx[r] = fmaxf(sa[r], sb[r]);
      bool need = false;
#pragma unroll
      for (int r = 0; r < 4; ++r) need = need || (mx[r] > mrow[1][r] + THR);
      if (__any(need)) {
#pragma unroll
        for (int msk = 1; msk < 16; msk <<= 1)
#pragma unroll
          for (int r = 0; r < 4; ++r) mx[r] = fmaxf(mx[r], __shfl_xor(mx[r], msk));
#pragma unroll
        for (int r = 0; r < 4; ++r) {
          float mn = fmaxf(mrow[1][r], mx[r]);
          float sc = exp2f(mrow[1][r] - mn);
          mrow[1][r] = mn; lsum[1][r] *= sc;
#pragma unroll
          for (int ct = 0; ct < 4; ++ct) acc[1][ct][r] *= sc;
        }
      }
#pragma unroll
      for (int r = 0; r < 4; ++r) {
        int row = 16 + 4 * g + r;
        int sw  = (row & 7) << 3;
        float pa = exp2f(sa[r] - mrow[1][r]);
        float pb = exp2f(sb[r] - mrow[1][r]);
        lsum[1][r] += pa + pb;
        sPw[row * 64 + ((hof + xl) ^ sw)]      = f2bf_trunc(pa);
        sPw[row * 64 + ((hof + 16 + xl) ^ sw)] = f2bf_trunc(pb);
      }
    }

    // ---- PV for both blks (this wave's 64 channels) ----
    {
      int row0 = xl, row1 = 16 + xl;
      bf16x8 pf0 = *(const bf16x8*)(sPw + row0 * 64 + ((hof + 8 * g) ^ ((row0 & 7) << 3)));
      bf16x8 pf1 = *(const bf16x8*)(sPw + row1 * 64 + ((hof + 8 * g) ^ ((row1 & 7) << 3)));
#pragma unroll
      for (int ct = 0; ct < 4; ++ct) {
        acc[0][ct] = __builtin_amdgcn_mfma_f32_16x16x32_bf16(pf0, vf[ct], acc[0][ct], 0, 0, 0);
        acc[1][ct] = __builtin_amdgcn_mfma_f32_16x16x32_bf16(pf1, vf[ct], acc[1][ct], 0, 0, 0);
      }
    }
  }

  // ---- final l reduction (once) ----
#pragma unroll
  for (int msk = 1; msk < 16; msk <<= 1)
#pragma unroll
    for (int blk = 0; blk < 2; ++blk)
#pragma unroll
      for (int r = 0; r < 4; ++r)
        lsum[blk][r] += __shfl_xor(lsum[blk][r], msk);

  float linv[2][4];
#pragma unroll
  for (int blk = 0; blk < 2; ++blk)
#pragma unroll
    for (int r = 0; r < 4; ++r) linv[blk][r] = 1.f / lsum[blk][r];

  // ---- epilogue: out = gamma * acc/l + x, direct float4 RMW ----
  const float gm = gamma[0];
#pragma unroll
  for (int blk = 0; blk < 2; ++blk)
#pragma unroll
    for (int ct = 0; ct < 4; ++ct) {
      int c = w * 64 + ct * 16 + xl;
      size_t off = ((size_t)b * NC + c) * NN + i0 + blk * 16 + 4 * g;
      float4 xv = ld4(x + off);
      float4 o4;
      o4.x = fmaf(gm, acc[blk][ct][0] * linv[blk][0], xv.x);
      o4.y = fmaf(gm, acc[blk][ct][1] * linv[blk][1], xv.y);
      o4.z = fmaf(gm, acc[blk][ct][2] * linv[blk][2], xv.z);
      o4.w = fmaf(gm, acc[blk][ct][3] * linv[blk][3], xv.w);
      st4(out + off, o4);
    }
}

// ---------------------------------------------------------------------------
extern "C" void kernel_launch(void* const* d_in, const int* in_sizes, int n_in,
                              void* d_out, int out_size, void* d_ws, size_t ws_size,
                              hipStream_t stream) {
  const float* x     = (const float*)d_in[0];
  const float* wq    = (const float*)d_in[1];
  const float* bq    = (const float*)d_in[2];
  const float* gq    = (const float*)d_in[3];
  const float* betaq = (const float*)d_in[4];
  const float* mq    = (const float*)d_in[5];
  const float* vq    = (const float*)d_in[6];
  const float* wk    = (const float*)d_in[7];
  const float* bk    = (const float*)d_in[8];
  const float* gk    = (const float*)d_in[9];
  const float* betak = (const float*)d_in[10];
  const float* mk    = (const float*)d_in[11];
  const float* vk    = (const float*)d_in[12];
  const float* wv    = (const float*)d_in[13];
  const float* bv    = (const float*)d_in[14];
  const float* gv    = (const float*)d_in[15];
  const float* betav = (const float*)d_in[16];
  const float* mv    = (const float*)d_in[17];
  const float* vv    = (const float*)d_in[18];
  const float* gamma = (const float*)d_in[19];
  float* out = (float*)d_out;

  u16* q_bf = (u16*)d_ws;
  u16* k_bf = q_bf + (size_t)NB * NN * 32;
  u16* v_bf = k_bf + (size_t)NB * NN * 32;

  qkv_fused<<<dim3(1280), dim3(256), 0, stream>>>(
      x, wq, bq, gq, betaq, mq, vq,
      wk, bk, gk, betak, mk, vk,
      wv, bv, gv, betav, mv, vv,
      q_bf, k_bf, v_bf);

  attn_mfma<<<dim3(1024), dim3(256), 0, stream>>>(q_bf, k_bf, v_bf, x, gamma, out);
}